// Round 1
// baseline (44.932 us; speedup 1.0000x reference)
//
#include <hip/hip_runtime.h>
#include <cstdint>
#include <cstddef>

// HyperNetwork: k[b,c,f] = sum_n x[b,c,n] * W_eff[c,f,n] + b_eff[c,f]
//   W_eff[c,f,n] = sum_z W_out[f,z] * W_in[c,z,n]
//   b_eff[c,f]   = sum_z b_in[c,z]  * W_out[f,z] + b_out[f]
// Output [B,1,C,3,3] flat == [B,C,9] since OUT_CH==1.

#define BB 256
#define CC 512
#define NZ 256
#define ZD 64
#define NF 9
#define XROW 260   // padded LDS row stride (floats); 260*4=1040B, 16B-aligned

typedef __attribute__((ext_vector_type(4))) float f32x4;

__device__ __forceinline__ void gload_lds16(const float* g, float* l) {
  __builtin_amdgcn_global_load_lds(
      (const __attribute__((address_space(1))) void*)g,
      (__attribute__((address_space(3))) void*)l,
      16, 0, 0);
}

__global__ __launch_bounds__(256, 2)
void hyper_fused(const float* __restrict__ z,
                 const float* __restrict__ W_in,
                 const float* __restrict__ b_in,
                 const float* __restrict__ W_out,
                 const float* __restrict__ b_out,
                 float* __restrict__ out)
{
  __shared__ __align__(16) float w_lds[NF * NZ];   // 9216 B  W_eff[f][n]
  __shared__ float b_lds[16];                      // b_eff
  __shared__ __align__(16) float x_lds[64 * XROW]; // 66560 B (64 b-rows)

  float* part = x_lds;  // aliased after compute: [wave][b_row][f] = 4*64*9 floats

  const int c    = blockIdx.x;
  const int t    = threadIdx.x;
  const int lane = t & 63;
  const int w    = t >> 6;

  // ---------- Phase 1: W_eff[f][n] for n = t ----------
  {
    float acc[NF];
    #pragma unroll
    for (int f = 0; f < NF; ++f) acc[f] = 0.f;
    const float* wi = W_in + (size_t)c * ZD * NZ + t;
    for (int zz = 0; zz < ZD; ++zz) {
      float v = wi[(size_t)zz * NZ];
      #pragma unroll
      for (int f = 0; f < NF; ++f)
        acc[f] += W_out[f * ZD + zz] * v;   // W_out uniform -> s_load
    }
    #pragma unroll
    for (int f = 0; f < NF; ++f)
      w_lds[f * NZ + t] = acc[f];
  }
  if (t < NF) {
    float bacc = b_out[t];
    for (int zz = 0; zz < ZD; ++zz)
      bacc += b_in[(size_t)c * ZD + zz] * W_out[t * ZD + zz];
    b_lds[t] = bacc;
  }

  __syncthreads();

  // ---------- Phase 2: 4 chunks of 64 batch rows ----------
  for (int bc = 0; bc < 4; ++bc) {
    // stage: wave w stages rows w*16 .. w*16+15 (one 1KB row per instr)
    {
      const int r0 = w * 16;
      #pragma unroll
      for (int j = 0; j < 16; ++j) {
        const int r = r0 + j;
        const int b = bc * 64 + r;
        const float* g = z + ((size_t)b * CC + c) * NZ + lane * 4;
        gload_lds16(g, &x_lds[r * XROW]);
      }
    }
    __syncthreads();  // drains vmcnt before barrier (compiler-inserted)

    // compute: lane owns b = bc*64+lane (row=lane), wave owns n-quarter
    float acc[NF];
    #pragma unroll
    for (int f = 0; f < NF; ++f) acc[f] = 0.f;
    {
      const int n0 = w * 64;
      #pragma unroll
      for (int g4 = 0; g4 < 16; ++g4) {
        f32x4 xv = *(const f32x4*)&x_lds[lane * XROW + n0 + g4 * 4];
        #pragma unroll
        for (int f = 0; f < NF; ++f) {
          f32x4 wf = *(const f32x4*)&w_lds[f * NZ + n0 + g4 * 4]; // uniform bcast
          acc[f] += xv.x * wf.x;
          acc[f] += xv.y * wf.y;
          acc[f] += xv.z * wf.z;
          acc[f] += xv.w * wf.w;
        }
      }
    }
    __syncthreads();  // done reading x_lds; part aliases it

    #pragma unroll
    for (int f = 0; f < NF; ++f)
      part[(w * 64 + lane) * NF + f] = acc[f];

    __syncthreads();

    // reduce across the 4 waves + store
    {
      const int b = bc * 64 + lane;
      for (int f = w; f < NF; f += 4) {
        float s = part[(0 * 64 + lane) * NF + f]
                + part[(1 * 64 + lane) * NF + f]
                + part[(2 * 64 + lane) * NF + f]
                + part[(3 * 64 + lane) * NF + f];
        out[((size_t)b * CC + c) * NF + f] = s + b_lds[f];
      }
    }
    __syncthreads();  // part (x_lds) consumed; safe to restage
  }
}

extern "C" void kernel_launch(void* const* d_in, const int* in_sizes, int n_in,
                              void* d_out, int out_size, void* d_ws, size_t ws_size,
                              hipStream_t stream) {
  const float* z     = (const float*)d_in[0];
  const float* W_in  = (const float*)d_in[1];
  const float* b_in  = (const float*)d_in[2];
  const float* W_out = (const float*)d_in[3];
  const float* b_out = (const float*)d_in[4];
  float* out = (float*)d_out;

  hipLaunchKernelGGL(hyper_fused, dim3(CC), dim3(256), 0, stream,
                     z, W_in, b_in, W_out, b_out, out);
}